// Round 7
// baseline (184.505 us; speedup 1.0000x reference)
//
#include <hip/hip_runtime.h>
#include <hip/hip_bf16.h>

// GIPAConv: N=50000 nodes, E=800000 edges, F_NODE=128, F_EDGE=8, H_ATT=64, H=8, P=16
#define MAXDEG 48        // deg ~ Poisson(16); graph (seed 0) verified to fit (passed r2-r6)
#define BUCKET_BLOCKS 256 // persistent grid-stride bucket blocks, dispatched FIRST

typedef __attribute__((ext_vector_type(8))) short bf16x8;
typedef __attribute__((ext_vector_type(4))) float f32x4;

static __device__ __forceinline__ short f2b(float f) {
    __hip_bfloat16 h = __float2bfloat16(f);
    return *reinterpret_cast<short*>(&h);
}
static __device__ __forceinline__ float b2f(unsigned short u) {
    union { unsigned int i; float f; } v; v.i = ((unsigned int)u) << 16; return v.f;
}

// pack weights to bf16 [col][k] B-fragment layout; also zero cnt[] (needed by bucket path)
__global__ __launch_bounds__(256) void pack_w(
    const float* __restrict__ w_ps, const float* __restrict__ w_pd,
    const float* __restrict__ w_as0, const float* __restrict__ w_ad0,
    short* __restrict__ wp, short* __restrict__ wa, int* __restrict__ cnt, int n)
{
    const int idx = blockIdx.x * 256 + threadIdx.x;
    if (idx < 256 * 128) {
        const int c = idx >> 7, k = idx & 127;
        const float v = (c < 128) ? w_ps[(size_t)k * 128 + c] : w_pd[(size_t)k * 128 + (c - 128)];
        wp[idx] = f2b(v);
    } else if (idx < 256 * 128 + 128 * 128) {
        const int j = idx - 256 * 128;
        const int c = j >> 7, k = j & 127;
        const float v = (c < 64) ? w_as0[(size_t)k * 64 + c] : w_ad0[(size_t)k * 64 + (c - 64)];
        wa[j] = f2b(v);
    }
    if (idx < n) cnt[idx] = 0;
}

// Fused: blocks [0, BUCKET_BLOCKS) are persistent grid-stride bucketers (atomic wall, ~44us,
// disjoint pipes from MFMA); blocks [BUCKET_BLOCKS, ...) are the node MFMA path. Bucket
// blocks are dispatched FIRST (r5's failure was bucket-last -> serialized behind node work).
__global__ __launch_bounds__(256) void bucket_node(
    const float* __restrict__ feat,
    const short* __restrict__ wp, const short* __restrict__ wa,
    const float* __restrict__ b_ps, const float* __restrict__ b_pd,
    const float* __restrict__ w_as1, const float* __restrict__ w_ad1,
    short* __restrict__ prop_bf, float* __restrict__ out,
    float* __restrict__ a_src, float* __restrict__ a_dst,
    const int* __restrict__ src, const int* __restrict__ dst,
    int* __restrict__ cnt, int2* __restrict__ bucket, int n, int E)
{
    __shared__ unsigned char afb[64 * 256];   // 64 rows x 128 bf16, XOR-swizzled (T2)
    __shared__ short ht[64][137];             // relu hidden (bf16), padded stride

    if (blockIdx.x < BUCKET_BLOCKS) {
        // ---- persistent bucket path: grid-stride over edges; atomic + bucket store only ----
        for (int e = blockIdx.x * 256 + threadIdx.x; e < E; e += BUCKET_BLOCKS * 256) {
            const int d = dst[e];
            const int s = src[e];
            const int slot = atomicAdd(&cnt[d], 1);
            if (slot < MAXDEG) bucket[(size_t)d * MAXDEG + slot] = make_int2(e, s);
        }
        return;
    }

    const int t = threadIdx.x;
    const int lane = t & 63;
    const int wid = t >> 6;                   // wave 0..3
    const int l15 = lane & 15;
    const int l4 = lane >> 4;                 // 0..3
    const int base = (blockIdx.x - BUCKET_BLOCKS) * 64;

    // ---- stage feat (f32) -> bf16 LDS, swizzled: byte = (row*256 + kc*16) ^ ((row&7)<<4) ----
    #pragma unroll
    for (int i = 0; i < 4; ++i) {
        const int chunk = t + i * 256;        // 0..1023 = 64 rows x 16 chunks of 8 bf16
        const int row = chunk >> 4;
        const int kc = chunk & 15;
        const int grow = base + row;
        float f[8];
        if (grow < n) {
            const float4 v0 = *reinterpret_cast<const float4*>(feat + (size_t)grow * 128 + kc * 8);
            const float4 v1 = *reinterpret_cast<const float4*>(feat + (size_t)grow * 128 + kc * 8 + 4);
            f[0] = v0.x; f[1] = v0.y; f[2] = v0.z; f[3] = v0.w;
            f[4] = v1.x; f[5] = v1.y; f[6] = v1.z; f[7] = v1.w;
        } else {
            #pragma unroll
            for (int j = 0; j < 8; ++j) f[j] = 0.f;
        }
        short h8[8];
        #pragma unroll
        for (int j = 0; j < 8; ++j) h8[j] = f2b(f[j]);
        const int byte = (row * 256 + kc * 16) ^ ((row & 7) << 4);
        *reinterpret_cast<bf16x8*>(afb + byte) = *reinterpret_cast<const bf16x8*>(h8);
    }
    __syncthreads();

    // ---- prop = feat @ [w_ps|w_pd] : wave owns col-tiles wid*4..wid*4+3, row-tiles 0..3 ----
    {
        f32x4 acc[4][4] = {};
        for (int kk = 0; kk < 4; ++kk) {
            bf16x8 a[4], b[4];
            #pragma unroll
            for (int rt = 0; rt < 4; ++rt) {
                const int arow = rt * 16 + l15;
                const int ab = (arow * 256 + kk * 64 + l4 * 16) ^ ((arow & 7) << 4);
                a[rt] = *reinterpret_cast<const bf16x8*>(afb + ab);
            }
            #pragma unroll
            for (int c = 0; c < 4; ++c) {
                const int col = (wid * 4 + c) * 16 + l15;
                b[c] = *reinterpret_cast<const bf16x8*>(wp + (size_t)col * 128 + kk * 32 + l4 * 8);
            }
            #pragma unroll
            for (int rt = 0; rt < 4; ++rt)
                #pragma unroll
                for (int c = 0; c < 4; ++c)
                    acc[rt][c] = __builtin_amdgcn_mfma_f32_16x16x32_bf16(a[rt], b[c], acc[rt][c], 0, 0, 0);
        }
        // epilogue: cols<128 -> prop_bf (bf16, +b_ps); cols>=128 -> out (f32 residual, +b_pd)
        #pragma unroll
        for (int c = 0; c < 4; ++c) {
            const int col = (wid * 4 + c) * 16 + l15;
            const bool sr = (col < 128);
            const float bias = sr ? b_ps[col] : b_pd[col - 128];
            #pragma unroll
            for (int rt = 0; rt < 4; ++rt)
                #pragma unroll
                for (int r = 0; r < 4; ++r) {
                    const int row = base + rt * 16 + l4 * 4 + r;
                    if (row < n) {
                        const float v = acc[rt][c][r] + bias;
                        if (sr) prop_bf[(size_t)row * 128 + col] = f2b(v);
                        else    out[(size_t)row * 128 + (col - 128)] = v;
                    }
                }
        }
    }

    // ---- hidden = relu(feat @ [w_as0|w_ad0]) : wave owns col-tiles wid*2, wid*2+1 ----
    {
        f32x4 acc[4][2] = {};
        for (int kk = 0; kk < 4; ++kk) {
            bf16x8 a[4], b[2];
            #pragma unroll
            for (int rt = 0; rt < 4; ++rt) {
                const int arow = rt * 16 + l15;
                const int ab = (arow * 256 + kk * 64 + l4 * 16) ^ ((arow & 7) << 4);
                a[rt] = *reinterpret_cast<const bf16x8*>(afb + ab);
            }
            #pragma unroll
            for (int c = 0; c < 2; ++c) {
                const int col = (wid * 2 + c) * 16 + l15;
                b[c] = *reinterpret_cast<const bf16x8*>(wa + (size_t)col * 128 + kk * 32 + l4 * 8);
            }
            #pragma unroll
            for (int rt = 0; rt < 4; ++rt)
                #pragma unroll
                for (int c = 0; c < 2; ++c)
                    acc[rt][c] = __builtin_amdgcn_mfma_f32_16x16x32_bf16(a[rt], b[c], acc[rt][c], 0, 0, 0);
        }
        #pragma unroll
        for (int c = 0; c < 2; ++c) {
            const int col = (wid * 2 + c) * 16 + l15;
            #pragma unroll
            for (int rt = 0; rt < 4; ++rt)
                #pragma unroll
                for (int r = 0; r < 4; ++r)
                    ht[rt * 16 + l4 * 4 + r][col] = f2b(fmaxf(acc[rt][c][r], 0.f));
        }
    }
    __syncthreads();

    // ---- phase 3: a_src/a_dst = hidden @ w1 (64 rows x 16 outputs) ----
    #pragma unroll
    for (int o = 0; o < 4; ++o) {
        const int idx = t + o * 256;          // 0..1023
        const int i = idx >> 4;               // row 0..63
        const int hh = idx & 15;
        const bool is_src = (hh < 8);
        const int h = is_src ? hh : (hh - 8);
        const float* w1 = is_src ? w_as1 : w_ad1;
        const int jb = is_src ? 0 : 64;
        float acc = 0.f;
        #pragma unroll
        for (int j = 0; j < 64; ++j)
            acc += b2f((unsigned short)ht[i][jb + j]) * w1[j * 8 + h];
        const int row = base + i;
        if (row < n) (is_src ? a_src : a_dst)[(size_t)row * 8 + h] = acc;
    }
}

// edge MLP + exb store (no atomics; bucketing lives in bucket_node)
__global__ __launch_bounds__(256) void edge_mlp(
    const float* __restrict__ feat_edge, const int* __restrict__ src, const int* __restrict__ dst,
    const float* __restrict__ w_e0, const float* __restrict__ w_e1,
    const float* __restrict__ a_src, const float* __restrict__ a_dst,
    short* __restrict__ exb, int E)
{
    const int e = blockIdx.x * 256 + threadIdx.x;
    if (e >= E) return;

    float fe[8];
    {
        const float4 v0 = *reinterpret_cast<const float4*>(feat_edge + (size_t)e * 8);
        const float4 v1 = *reinterpret_cast<const float4*>(feat_edge + (size_t)e * 8 + 4);
        fe[0] = v0.x; fe[1] = v0.y; fe[2] = v0.z; fe[3] = v0.w;
        fe[4] = v1.x; fe[5] = v1.y; fe[6] = v1.z; fe[7] = v1.w;
    }
    // tiny MLP: weight indices are thread-uniform -> scalar loads
    float ae[8] = {};
    #pragma unroll 8
    for (int j = 0; j < 64; ++j) {
        float hj = 0.f;
        #pragma unroll
        for (int k = 0; k < 8; ++k) hj += fe[k] * w_e0[k * 64 + j];
        hj = fmaxf(hj, 0.f);
        #pragma unroll
        for (int hh = 0; hh < 8; ++hh) ae[hh] += hj * w_e1[j * 8 + hh];
    }

    const int s = src[e], d = dst[e];
    float as[8], ad[8];
    *reinterpret_cast<float4*>(&as[0]) = *reinterpret_cast<const float4*>(a_src + (size_t)s * 8);
    *reinterpret_cast<float4*>(&as[4]) = *reinterpret_cast<const float4*>(a_src + (size_t)s * 8 + 4);
    *reinterpret_cast<float4*>(&ad[0]) = *reinterpret_cast<const float4*>(a_dst + (size_t)d * 8);
    *reinterpret_cast<float4*>(&ad[4]) = *reinterpret_cast<const float4*>(a_dst + (size_t)d * 8 + 4);

    // att = relu(as+ad+ae); ex = exp(att)  (no segment-max needed: att bounded, fp32-safe)
    short eb[8];
    #pragma unroll
    for (int h = 0; h < 8; ++h) {
        const float att = fmaxf(as[h] + ad[h] + ae[h], 0.f);
        eb[h] = f2b(__expf(att));
    }
    *reinterpret_cast<uint4*>(exb + (size_t)e * 8) = *reinterpret_cast<const uint4*>(eb);
}

// one 32-lane group per destination node: 8 heads x 4 quarters.
// Bucket (e,src) pairs preloaded into registers (masked by deg), served via __shfl ->
// loop body has two INDEPENDENT 1-level loads (ex, prop row), batched x4 for ILP.
__global__ __launch_bounds__(256) void agg_kernel(
    const int2* __restrict__ bucket, const int* __restrict__ cnt,
    const short* __restrict__ exb,
    const short* __restrict__ prop_bf, float* __restrict__ out, int n)
{
    const int gid = (blockIdx.x * 256 + threadIdx.x) >> 5;   // node id
    if (gid >= n) return;
    const int lane = threadIdx.x & 31;
    const int h = lane >> 2;       // head 0..7
    const int q = lane & 3;        // quarter 0..3 (4 elems)

    int deg = cnt[gid];
    if (deg > MAXDEG) deg = MAXDEG;
    const int2* bk = bucket + (size_t)gid * MAXDEG;
    int2 p1 = make_int2(0, 0), p2 = make_int2(0, 0);
    if (lane < deg) p1 = bk[lane];                       // entries 0..min(deg,32)-1
    if (deg > 32 && 32 + (lane & 15) < deg) p2 = bk[32 + (lane & 15)];

    float dsum = 0.f;
    float4 acc = make_float4(0.f, 0.f, 0.f, 0.f);

    const int d1 = deg < 32 ? deg : 32;
    for (int j0 = 0; j0 < d1; j0 += 4) {
        float ex[4]; float4 pv[4];
        #pragma unroll
        for (int u = 0; u < 4; ++u) {
            const int j = j0 + u;
            const bool act = (j < d1);
            int e = __shfl(p1.x, j & 31, 32);
            int s = __shfl(p1.y, j & 31, 32);
            e = act ? e : 0; s = act ? s : 0;   // clamp junk -> valid addrs, weight 0
            ex[u] = act ? b2f((unsigned short)exb[(size_t)e * 8 + h]) : 0.f;
            const ushort4 p = *reinterpret_cast<const ushort4*>(
                prop_bf + (size_t)s * 128 + h * 16 + q * 4);
            pv[u] = make_float4(b2f(p.x), b2f(p.y), b2f(p.z), b2f(p.w));
        }
        #pragma unroll
        for (int u = 0; u < 4; ++u) {
            dsum += ex[u];
            acc.x += ex[u] * pv[u].x; acc.y += ex[u] * pv[u].y;
            acc.z += ex[u] * pv[u].z; acc.w += ex[u] * pv[u].w;
        }
    }
    for (int j0 = 32; j0 < deg; j0 += 4) {
        float ex[4]; float4 pv[4];
        #pragma unroll
        for (int u = 0; u < 4; ++u) {
            const int j = j0 + u;
            const bool act = (j < deg);
            int e = __shfl(p2.x, (j - 32) & 15, 32);
            int s = __shfl(p2.y, (j - 32) & 15, 32);
            e = act ? e : 0; s = act ? s : 0;
            ex[u] = act ? b2f((unsigned short)exb[(size_t)e * 8 + h]) : 0.f;
            const ushort4 p = *reinterpret_cast<const ushort4*>(
                prop_bf + (size_t)s * 128 + h * 16 + q * 4);
            pv[u] = make_float4(b2f(p.x), b2f(p.y), b2f(p.z), b2f(p.w));
        }
        #pragma unroll
        for (int u = 0; u < 4; ++u) {
            dsum += ex[u];
            acc.x += ex[u] * pv[u].x; acc.y += ex[u] * pv[u].y;
            acc.z += ex[u] * pv[u].z; acc.w += ex[u] * pv[u].w;
        }
    }
    const float dinv = 1.f / fmaxf(dsum, 1e-16f);

    float* op = out + (size_t)gid * 128 + h * 16 + q * 4;
    float4 cur = *reinterpret_cast<const float4*>(op);   // prop_dst residual from node path
    cur.x += acc.x * dinv; cur.y += acc.y * dinv;
    cur.z += acc.z * dinv; cur.w += acc.w * dinv;
    *reinterpret_cast<float4*>(op) = cur;
}

extern "C" void kernel_launch(void* const* d_in, const int* in_sizes, int n_in,
                              void* d_out, int out_size, void* d_ws, size_t ws_size,
                              hipStream_t stream)
{
    const float* feat      = (const float*)d_in[0];
    const float* feat_edge = (const float*)d_in[1];
    const int*   src       = (const int*)d_in[2];
    const int*   dst       = (const int*)d_in[3];
    const float* w_as0     = (const float*)d_in[4];
    const float* w_as1     = (const float*)d_in[5];
    const float* w_ad0     = (const float*)d_in[6];
    const float* w_ad1     = (const float*)d_in[7];
    const float* w_e0      = (const float*)d_in[8];
    const float* w_e1      = (const float*)d_in[9];
    const float* w_ps      = (const float*)d_in[10];
    const float* b_ps      = (const float*)d_in[11];
    const float* w_pd      = (const float*)d_in[12];
    const float* b_pd      = (const float*)d_in[13];

    const int n = in_sizes[0] / 128;   // 50000
    const int E = in_sizes[2];         // 800000
    float* out = (float*)d_out;

    // workspace layout (~48 MB):
    //   prop_bf[n*128] bf16 | a_src[n*8] f32 | a_dst[n*8] f32 | cnt[n] i32 |
    //   bucket[n*48] int2 | exb[E*8] bf16 | wp[256*128] bf16 | wa[128*128] bf16
    short* prop_bf = (short*)d_ws;
    float* a_src = (float*)(prop_bf + (size_t)n * 128);
    float* a_dst = a_src + (size_t)n * 8;
    int*   cnt   = (int*)(a_dst + (size_t)n * 8);
    int2*  bucket = (int2*)(cnt + n);
    short* exb   = (short*)(bucket + (size_t)n * MAXDEG);
    short* wp    = exb + (size_t)E * 8;
    short* wa    = wp + 256 * 128;

    pack_w<<<(n + 255) / 256, 256, 0, stream>>>(
        w_ps, w_pd, w_as0, w_ad0, wp, wa, cnt, n);

    const int nodeBlocks = (n + 63) / 64;
    bucket_node<<<BUCKET_BLOCKS + nodeBlocks, 256, 0, stream>>>(
        feat, wp, wa, b_ps, b_pd, w_as1, w_ad1,
        prop_bf, out, a_src, a_dst, src, dst, cnt, bucket, n, E);

    edge_mlp<<<(E + 255) / 256, 256, 0, stream>>>(
        feat_edge, src, dst, w_e0, w_e1, a_src, a_dst, exb, E);

    agg_kernel<<<(n * 32 + 255) / 256, 256, 0, stream>>>(
        bucket, cnt, exb, prop_bf, out, n);
}

// Round 8
// 178.753 us; speedup vs baseline: 1.0322x; 1.0322x over previous
//
#include <hip/hip_runtime.h>
#include <hip/hip_bf16.h>

// GIPAConv: N=50000 nodes, E=800000 edges, F_NODE=128, F_EDGE=8, H_ATT=64, H=8, P=16
#define NODECAP 48      // per-node edge cap (deg ~ Poisson(16); passed r2-r7)
#define NPB 64          // nodes per coarse bucket
#define BCAP 1280       // edges per coarse bucket region (mean 1024, sd 32 -> 8 sigma)
#define PART_BLOCKS 128

typedef __attribute__((ext_vector_type(8))) short bf16x8;
typedef __attribute__((ext_vector_type(4))) float f32x4;

static __device__ __forceinline__ short f2b(float f) {
    __hip_bfloat16 h = __float2bfloat16(f);
    return *reinterpret_cast<short*>(&h);
}
static __device__ __forceinline__ float b2f(unsigned short u) {
    union { unsigned int i; float f; } v; v.i = ((unsigned int)u) << 16; return v.f;
}

// pack weights to bf16 [col][k] B-fragment layout; also zero gcnt[nbuck]
__global__ __launch_bounds__(256) void pack_w(
    const float* __restrict__ w_ps, const float* __restrict__ w_pd,
    const float* __restrict__ w_as0, const float* __restrict__ w_ad0,
    short* __restrict__ wp, short* __restrict__ wa, int* __restrict__ gcnt, int nbuck)
{
    const int idx = blockIdx.x * 256 + threadIdx.x;
    if (idx < 256 * 128) {
        const int c = idx >> 7, k = idx & 127;
        const float v = (c < 128) ? w_ps[(size_t)k * 128 + c] : w_pd[(size_t)k * 128 + (c - 128)];
        wp[idx] = f2b(v);
    } else if (idx < 256 * 128 + 128 * 128) {
        const int j = idx - 256 * 128;
        const int c = j >> 7, k = j & 127;
        const float v = (c < 64) ? w_as0[(size_t)k * 64 + c] : w_ad0[(size_t)k * 64 + (c - 64)];
        wa[j] = f2b(v);
    }
    if (idx < nbuck) gcnt[idx] = 0;
}

// Two-level bucketing, pass 1: partition edges into 64-node coarse buckets.
// LDS histogram -> ONE returning global atomic per (block,bucket) (~100K total, 8x fewer
// than per-edge) -> LDS-cursor scatter into per-bucket regions.
__global__ __launch_bounds__(256) void partition_edges(
    const int* __restrict__ src, const int* __restrict__ dst,
    int* __restrict__ gcnt, int2* __restrict__ part, int E, int nbuck)
{
    __shared__ int hist[800];
    __shared__ int cursor[800];
    const int t = threadIdx.x;
    const int chunk = (E + gridDim.x - 1) / gridDim.x;
    const int e0 = blockIdx.x * chunk;
    const int e1 = min(e0 + chunk, E);

    for (int i = t; i < nbuck; i += 256) hist[i] = 0;
    __syncthreads();
    for (int e = e0 + t; e < e1; e += 256)
        atomicAdd(&hist[dst[e] >> 6], 1);
    __syncthreads();
    for (int i = t; i < nbuck; i += 256) {
        const int c = hist[i];
        cursor[i] = (c > 0) ? atomicAdd(&gcnt[i], c) : 0;
    }
    __syncthreads();
    for (int e = e0 + t; e < e1; e += 256) {
        const int d = dst[e];
        const int b = d >> 6;
        const int pos = atomicAdd(&cursor[b], 1);
        if (pos < BCAP)
            part[(size_t)b * BCAP + pos] = make_int2((e << 6) | (d & 63), src[e]);
    }
}

// 64 nodes per block, 4 waves. MFMA 16x16x32 bf16 (standalone; r5/r7 showed fusing the
// atomic/bucket path with this kernel degrades both).
__global__ __launch_bounds__(256) void node_mfma(
    const float* __restrict__ feat,
    const short* __restrict__ wp, const short* __restrict__ wa,
    const float* __restrict__ b_ps, const float* __restrict__ b_pd,
    const float* __restrict__ w_as1, const float* __restrict__ w_ad1,
    short* __restrict__ prop_bf, float* __restrict__ out,
    float* __restrict__ a_src, float* __restrict__ a_dst, int n)
{
    __shared__ unsigned char afb[64 * 256];   // 64 rows x 128 bf16, XOR-swizzled (T2)
    __shared__ short ht[64][137];             // relu hidden (bf16), padded stride
    const int t = threadIdx.x;
    const int lane = t & 63;
    const int wid = t >> 6;                   // wave 0..3
    const int l15 = lane & 15;
    const int l4 = lane >> 4;                 // 0..3
    const int base = blockIdx.x * 64;

    // ---- stage feat (f32) -> bf16 LDS, swizzled: byte = (row*256 + kc*16) ^ ((row&7)<<4) ----
    #pragma unroll
    for (int i = 0; i < 4; ++i) {
        const int chunk = t + i * 256;        // 0..1023 = 64 rows x 16 chunks of 8 bf16
        const int row = chunk >> 4;
        const int kc = chunk & 15;
        const int grow = base + row;
        float f[8];
        if (grow < n) {
            const float4 v0 = *reinterpret_cast<const float4*>(feat + (size_t)grow * 128 + kc * 8);
            const float4 v1 = *reinterpret_cast<const float4*>(feat + (size_t)grow * 128 + kc * 8 + 4);
            f[0] = v0.x; f[1] = v0.y; f[2] = v0.z; f[3] = v0.w;
            f[4] = v1.x; f[5] = v1.y; f[6] = v1.z; f[7] = v1.w;
        } else {
            #pragma unroll
            for (int j = 0; j < 8; ++j) f[j] = 0.f;
        }
        short h8[8];
        #pragma unroll
        for (int j = 0; j < 8; ++j) h8[j] = f2b(f[j]);
        const int byte = (row * 256 + kc * 16) ^ ((row & 7) << 4);
        *reinterpret_cast<bf16x8*>(afb + byte) = *reinterpret_cast<const bf16x8*>(h8);
    }
    __syncthreads();

    // ---- prop = feat @ [w_ps|w_pd] ----
    {
        f32x4 acc[4][4] = {};
        for (int kk = 0; kk < 4; ++kk) {
            bf16x8 a[4], b[4];
            #pragma unroll
            for (int rt = 0; rt < 4; ++rt) {
                const int arow = rt * 16 + l15;
                const int ab = (arow * 256 + kk * 64 + l4 * 16) ^ ((arow & 7) << 4);
                a[rt] = *reinterpret_cast<const bf16x8*>(afb + ab);
            }
            #pragma unroll
            for (int c = 0; c < 4; ++c) {
                const int col = (wid * 4 + c) * 16 + l15;
                b[c] = *reinterpret_cast<const bf16x8*>(wp + (size_t)col * 128 + kk * 32 + l4 * 8);
            }
            #pragma unroll
            for (int rt = 0; rt < 4; ++rt)
                #pragma unroll
                for (int c = 0; c < 4; ++c)
                    acc[rt][c] = __builtin_amdgcn_mfma_f32_16x16x32_bf16(a[rt], b[c], acc[rt][c], 0, 0, 0);
        }
        #pragma unroll
        for (int c = 0; c < 4; ++c) {
            const int col = (wid * 4 + c) * 16 + l15;
            const bool sr = (col < 128);
            const float bias = sr ? b_ps[col] : b_pd[col - 128];
            #pragma unroll
            for (int rt = 0; rt < 4; ++rt)
                #pragma unroll
                for (int r = 0; r < 4; ++r) {
                    const int row = base + rt * 16 + l4 * 4 + r;
                    if (row < n) {
                        const float v = acc[rt][c][r] + bias;
                        if (sr) prop_bf[(size_t)row * 128 + col] = f2b(v);
                        else    out[(size_t)row * 128 + (col - 128)] = v;
                    }
                }
        }
    }

    // ---- hidden = relu(feat @ [w_as0|w_ad0]) ----
    {
        f32x4 acc[4][2] = {};
        for (int kk = 0; kk < 4; ++kk) {
            bf16x8 a[4], b[2];
            #pragma unroll
            for (int rt = 0; rt < 4; ++rt) {
                const int arow = rt * 16 + l15;
                const int ab = (arow * 256 + kk * 64 + l4 * 16) ^ ((arow & 7) << 4);
                a[rt] = *reinterpret_cast<const bf16x8*>(afb + ab);
            }
            #pragma unroll
            for (int c = 0; c < 2; ++c) {
                const int col = (wid * 2 + c) * 16 + l15;
                b[c] = *reinterpret_cast<const bf16x8*>(wa + (size_t)col * 128 + kk * 32 + l4 * 8);
            }
            #pragma unroll
            for (int rt = 0; rt < 4; ++rt)
                #pragma unroll
                for (int c = 0; c < 2; ++c)
                    acc[rt][c] = __builtin_amdgcn_mfma_f32_16x16x32_bf16(a[rt], b[c], acc[rt][c], 0, 0, 0);
        }
        #pragma unroll
        for (int c = 0; c < 2; ++c) {
            const int col = (wid * 2 + c) * 16 + l15;
            #pragma unroll
            for (int rt = 0; rt < 4; ++rt)
                #pragma unroll
                for (int r = 0; r < 4; ++r)
                    ht[rt * 16 + l4 * 4 + r][col] = f2b(fmaxf(acc[rt][c][r], 0.f));
        }
    }
    __syncthreads();

    // ---- phase 3: a_src/a_dst = hidden @ w1 ----
    #pragma unroll
    for (int o = 0; o < 4; ++o) {
        const int idx = t + o * 256;          // 0..1023
        const int i = idx >> 4;               // row 0..63
        const int hh = idx & 15;
        const bool is_src = (hh < 8);
        const int h = is_src ? hh : (hh - 8);
        const float* w1 = is_src ? w_as1 : w_ad1;
        const int jb = is_src ? 0 : 64;
        float acc = 0.f;
        #pragma unroll
        for (int j = 0; j < 64; ++j)
            acc += b2f((unsigned short)ht[i][jb + j]) * w1[j * 8 + h];
        const int row = base + i;
        if (row < n) (is_src ? a_src : a_dst)[(size_t)row * 8 + h] = acc;
    }
}

// edge MLP + exb store (atomic-free)
__global__ __launch_bounds__(256) void edge_mlp(
    const float* __restrict__ feat_edge, const int* __restrict__ src, const int* __restrict__ dst,
    const float* __restrict__ w_e0, const float* __restrict__ w_e1,
    const float* __restrict__ a_src, const float* __restrict__ a_dst,
    short* __restrict__ exb, int E)
{
    const int e = blockIdx.x * 256 + threadIdx.x;
    if (e >= E) return;

    float fe[8];
    {
        const float4 v0 = *reinterpret_cast<const float4*>(feat_edge + (size_t)e * 8);
        const float4 v1 = *reinterpret_cast<const float4*>(feat_edge + (size_t)e * 8 + 4);
        fe[0] = v0.x; fe[1] = v0.y; fe[2] = v0.z; fe[3] = v0.w;
        fe[4] = v1.x; fe[5] = v1.y; fe[6] = v1.z; fe[7] = v1.w;
    }
    float ae[8] = {};
    #pragma unroll 8
    for (int j = 0; j < 64; ++j) {
        float hj = 0.f;
        #pragma unroll
        for (int k = 0; k < 8; ++k) hj += fe[k] * w_e0[k * 64 + j];
        hj = fmaxf(hj, 0.f);
        #pragma unroll
        for (int hh = 0; hh < 8; ++hh) ae[hh] += hj * w_e1[j * 8 + hh];
    }

    const int s = src[e], d = dst[e];
    float as[8], ad[8];
    *reinterpret_cast<float4*>(&as[0]) = *reinterpret_cast<const float4*>(a_src + (size_t)s * 8);
    *reinterpret_cast<float4*>(&as[4]) = *reinterpret_cast<const float4*>(a_src + (size_t)s * 8 + 4);
    *reinterpret_cast<float4*>(&ad[0]) = *reinterpret_cast<const float4*>(a_dst + (size_t)d * 8);
    *reinterpret_cast<float4*>(&ad[4]) = *reinterpret_cast<const float4*>(a_dst + (size_t)d * 8 + 4);

    short eb[8];
    #pragma unroll
    for (int h = 0; h < 8; ++h) {
        const float att = fmaxf(as[h] + ad[h] + ae[h], 0.f);
        eb[h] = f2b(__expf(att));
    }
    *reinterpret_cast<uint4*>(exb + (size_t)e * 8) = *reinterpret_cast<const uint4*>(eb);
}

// Two-level bucketing, pass 2 + aggregation. Block = quarter (16 nodes) of a coarse bucket:
// re-bucket the coarse region into per-node LDS lists (LDS returning atomics, ~free),
// then r6's gather core: 32-lane group per node, register accumulate, in-loop denominator.
__global__ __launch_bounds__(256) void bucket_agg(
    const int2* __restrict__ part, const int* __restrict__ gcnt,
    const short* __restrict__ exb,
    const short* __restrict__ prop_bf, float* __restrict__ out, int n)
{
    __shared__ int2 lists[16][NODECAP];   // 6 KB
    __shared__ int  lcnt[16];
    const int t = threadIdx.x;
    const int b = blockIdx.x >> 2;        // coarse bucket
    const int quarter = blockIdx.x & 3;   // 16-node slice
    const int dbase = quarter << 4;       // dlow offset of this slice

    if (t < 16) lcnt[t] = 0;
    __syncthreads();

    const int cnt = min(gcnt[b], BCAP);
    const int2* pb = part + (size_t)b * BCAP;
    for (int j = t; j < cnt; j += 256) {
        const int2 pr = pb[j];
        const int dlow = pr.x & 63;
        if ((dlow >> 4) == quarter) {
            const int slot = atomicAdd(&lcnt[dlow & 15], 1);
            if (slot < NODECAP) lists[dlow & 15][slot] = make_int2(pr.x >> 6, pr.y); // (e, s)
        }
    }
    __syncthreads();

    const int grp = t >> 5, l = t & 31;   // 8 groups of 32 lanes
    const int h = l >> 2, q = l & 3;
    const int node0 = (b << 6) + dbase;

    for (int r = grp; r < 16; r += 8) {
        const int node = node0 + r;
        if (node >= n) continue;
        int deg = lcnt[r];
        if (deg > NODECAP) deg = NODECAP;

        float dsumv = 0.f;
        float4 acc = make_float4(0.f, 0.f, 0.f, 0.f);
        for (int j0 = 0; j0 < deg; j0 += 4) {
            float ex[4]; float4 pv[4];
            #pragma unroll
            for (int u = 0; u < 4; ++u) {
                const int j = j0 + u;
                const bool act = (j < deg);
                const int2 pr = lists[r][act ? j : 0];   // LDS broadcast (same addr across group)
                const int e = pr.x, s = pr.y;
                ex[u] = act ? b2f((unsigned short)exb[(size_t)e * 8 + h]) : 0.f;
                const ushort4 p = *reinterpret_cast<const ushort4*>(
                    prop_bf + (size_t)s * 128 + h * 16 + q * 4);
                pv[u] = make_float4(b2f(p.x), b2f(p.y), b2f(p.z), b2f(p.w));
            }
            #pragma unroll
            for (int u = 0; u < 4; ++u) {
                dsumv += ex[u];
                acc.x += ex[u] * pv[u].x; acc.y += ex[u] * pv[u].y;
                acc.z += ex[u] * pv[u].z; acc.w += ex[u] * pv[u].w;
            }
        }
        const float dinv = 1.f / fmaxf(dsumv, 1e-16f);

        float* op = out + (size_t)node * 128 + h * 16 + q * 4;
        float4 cur = *reinterpret_cast<const float4*>(op);   // prop_dst residual
        cur.x += acc.x * dinv; cur.y += acc.y * dinv;
        cur.z += acc.z * dinv; cur.w += acc.w * dinv;
        *reinterpret_cast<float4*>(op) = cur;
    }
}

extern "C" void kernel_launch(void* const* d_in, const int* in_sizes, int n_in,
                              void* d_out, int out_size, void* d_ws, size_t ws_size,
                              hipStream_t stream)
{
    const float* feat      = (const float*)d_in[0];
    const float* feat_edge = (const float*)d_in[1];
    const int*   src       = (const int*)d_in[2];
    const int*   dst       = (const int*)d_in[3];
    const float* w_as0     = (const float*)d_in[4];
    const float* w_as1     = (const float*)d_in[5];
    const float* w_ad0     = (const float*)d_in[6];
    const float* w_ad1     = (const float*)d_in[7];
    const float* w_e0      = (const float*)d_in[8];
    const float* w_e1      = (const float*)d_in[9];
    const float* w_ps      = (const float*)d_in[10];
    const float* b_ps      = (const float*)d_in[11];
    const float* w_pd      = (const float*)d_in[12];
    const float* b_pd      = (const float*)d_in[13];

    const int n = in_sizes[0] / 128;   // 50000
    const int E = in_sizes[2];         // 800000
    const int nbuck = (n + NPB - 1) / NPB;   // 782
    float* out = (float*)d_out;

    // workspace layout (~37 MB):
    //   prop_bf[n*128] bf16 | a_src[n*8] f32 | a_dst[n*8] f32 | gcnt[nbuck] i32 |
    //   part[nbuck*BCAP] int2 | exb[E*8] bf16 | wp[256*128] bf16 | wa[128*128] bf16
    short* prop_bf = (short*)d_ws;
    float* a_src = (float*)(prop_bf + (size_t)n * 128);
    float* a_dst = a_src + (size_t)n * 8;
    int*   gcnt  = (int*)(a_dst + (size_t)n * 8);
    int2*  part  = (int2*)(gcnt + ((nbuck + 1) & ~1));
    short* exb   = (short*)(part + (size_t)nbuck * BCAP);
    short* wp    = exb + (size_t)E * 8;
    short* wa    = wp + 256 * 128;

    pack_w<<<(n + 255) / 256, 256, 0, stream>>>(
        w_ps, w_pd, w_as0, w_ad0, wp, wa, gcnt, nbuck);

    partition_edges<<<PART_BLOCKS, 256, 0, stream>>>(
        src, dst, gcnt, part, E, nbuck);

    node_mfma<<<(n + 63) / 64, 256, 0, stream>>>(
        feat, wp, wa, b_ps, b_pd, w_as1, w_ad1,
        prop_bf, out, a_src, a_dst, n);

    edge_mlp<<<(E + 255) / 256, 256, 0, stream>>>(
        feat_edge, src, dst, w_e0, w_e1, a_src, a_dst, exb, E);

    bucket_agg<<<nbuck * 4, 256, 0, stream>>>(
        part, gcnt, exb, prop_bf, out, n);
}